// Round 6
// baseline (502.096 us; speedup 1.0000x reference)
//
#include <hip/hip_runtime.h>

#define NCLASS 1000
#define D 64
#define WARMUP 1000
#define CAP 2304            // per-class slot capacity: mean 2000 + ~6.8 sigma
#define SPILL_MAX 65536
#define K4_TPB 1024
#define UNR 8               // k4: outstanding row-loads per thread

typedef float f32x4 __attribute__((ext_vector_type(4)));
typedef int   i32x4 __attribute__((ext_vector_type(4)));

// ws layout (bytes)
#define OFF_CURSOR     0          // NCLASS ints
#define OFF_SPILLCNT   4096       // 1 int
#define OFF_SPILLSUM   8192       // NCLASS*D floats (256 KB)
#define OFF_SPILLROWS  270336     // SPILL_MAX ints (256 KB)
#define OFF_SORTED     1048576    // NCLASS*CAP ints (9.216 MB)

// ---------------------------------------------------------------------------
// Z0: zero cursors + spill count + spill sums (65,001 words)
__global__ __launch_bounds__(1024)
void z0_zero(int* __restrict__ ws_base) {
    const int i = blockIdx.x * 1024 + threadIdx.x;
    if (i < NCLASS + 1 + NCLASS * D) {
        if (i < NCLASS)            ws_base[OFF_CURSOR / 4 + i] = 0;
        else if (i == NCLASS)      ws_base[OFF_SPILLCNT / 4] = 0;
        else                       ws_base[OFF_SPILLSUM / 4 + (i - NCLASS - 1)] = 0;
    }
}

// ---------------------------------------------------------------------------
// S1: direct scatter — one global atomic rank per row, write into fixed-CAP
// class slot. Replaces histogram + 2 scans + LDS-cursor scatter.
__global__ __launch_bounds__(512)
void s1_scatter(const int* __restrict__ label, int n4,
                int* __restrict__ cursor, int* __restrict__ sorted_idx,
                int* __restrict__ spill_cnt, int* __restrict__ spill_rows)
{
    const int t = blockIdx.x * 512 + threadIdx.x;
    const int stride = gridDim.x * 512;
    for (int q = t; q < n4; q += stride) {
        const i32x4 l4 = *reinterpret_cast<const i32x4*>(label + q * 4);
        #pragma unroll
        for (int u = 0; u < 4; ++u) {
            const int r = q * 4 + u;
            const int l = l4[u];
            const int pos = atomicAdd(&cursor[l], 1);
            if (pos < CAP) {
                sorted_idx[l * CAP + pos] = r;
            } else {
                const int sp = atomicAdd(spill_cnt, 1);
                if (sp < SPILL_MAX) spill_rows[sp] = r;
            }
        }
    }
}

// ---------------------------------------------------------------------------
// S2: spill fixup (normally zero iterations) — fp32 global atomics into
// spill_sums[c][d]; k4 adds them in its finalize.
__global__ __launch_bounds__(256)
void s2_spill(const float* __restrict__ feat, const int* __restrict__ label,
              const int* __restrict__ spill_cnt, const int* __restrict__ spill_rows,
              float* __restrict__ spill_sums)
{
    const int ns = min(*spill_cnt, SPILL_MAX);
    const int lane = threadIdx.x & 63;
    const int wv   = (blockIdx.x * 256 + threadIdx.x) >> 6;
    const int nwv  = (gridDim.x * 256) >> 6;
    for (int e = wv; e < ns; e += nwv) {
        const int r = spill_rows[e];
        const int l = label[r];
        atomicAdd(&spill_sums[l * D + lane], feat[(size_t)r * D + lane]);
    }
}

// ---------------------------------------------------------------------------
// K4: one block per class. Gather rows via sorted_idx, accumulate in
// registers (NO atomics), 8-deep unroll, non-temporal loads, shuffle+LDS
// reduce, fused mean/EMA/spill finalize.
// Thread layout: slot = tid>>4 (64 row slots), col = tid&15 (float4 column).
__global__ __launch_bounds__(K4_TPB, 4)
void k4_reduce(const float* __restrict__ feat, const int* __restrict__ sorted_idx,
               const int* __restrict__ cursor, const float* __restrict__ spill_sums,
               const float* __restrict__ proto, const int* __restrict__ step_ptr,
               float* __restrict__ out)
{
    __shared__ float red[16][D];
    const int c   = blockIdx.x;
    const int tot = cursor[c];              // true class count
    const int cnt = min(tot, CAP);          // rows present in slots
    const int st  = c * CAP;
    const int tid = threadIdx.x;
    const int slot = tid >> 4;
    const int col  = tid & 15;

    f32x4 acc0 = {0.f, 0.f, 0.f, 0.f};
    f32x4 acc1 = {0.f, 0.f, 0.f, 0.f};
    int j = slot;
    for (; j + (UNR - 1) * 64 < cnt; j += UNR * 64) {
        int rr[UNR];
        #pragma unroll
        for (int u = 0; u < UNR; ++u)
            rr[u] = sorted_idx[st + j + u * 64];
        f32x4 v[UNR];
        #pragma unroll
        for (int u = 0; u < UNR; ++u)
            v[u] = __builtin_nontemporal_load((const f32x4*)(feat + (size_t)rr[u] * D + col * 4));
        #pragma unroll
        for (int u = 0; u < UNR; u += 2) {
            acc0 += v[u];
            acc1 += v[u + 1];
        }
    }
    for (; j < cnt; j += 64) {
        const int r = sorted_idx[st + j];
        acc0 += __builtin_nontemporal_load((const f32x4*)(feat + (size_t)r * D + col * 4));
    }
    acc0 += acc1;

    // reduce the 4 slots within each wave (slot differs in tid bits 4-5)
    #pragma unroll
    for (int m = 16; m <= 32; m <<= 1) {
        acc0[0] += __shfl_xor(acc0[0], m);
        acc0[1] += __shfl_xor(acc0[1], m);
        acc0[2] += __shfl_xor(acc0[2], m);
        acc0[3] += __shfl_xor(acc0[3], m);
    }
    const int wv = tid >> 6;                 // wave id 0..15
    if ((tid & 63) < 16) {                   // lanes 0..15 hold col sums
        red[wv][col * 4 + 0] = acc0[0];
        red[wv][col * 4 + 1] = acc0[1];
        red[wv][col * 4 + 2] = acc0[2];
        red[wv][col * 4 + 3] = acc0[3];
    }
    __syncthreads();

    if (tid < D) {
        float s = 0.f;
        #pragma unroll
        for (int k = 0; k < 16; ++k) s += red[k][tid];
        s += spill_sums[c * D + tid];        // normally 0
        const float mean = s / (float)(tot > 0 ? tot : 1);
        const float p    = proto[c * D + tid];
        const unsigned long long nz = __ballot(p != 0.0f);
        const bool use_new = (nz == 0ULL) || (step_ptr[0] <= WARMUP);
        const float upd = use_new ? mean : (0.9f * p + 0.1f * mean);
        out[c * D + tid] = (tot > 0) ? upd : p;
    }
}

// ---------------------------------------------------------------------------
extern "C" void kernel_launch(void* const* d_in, const int* in_sizes, int n_in,
                              void* d_out, int out_size, void* d_ws, size_t ws_size,
                              hipStream_t stream)
{
    const float* proto = (const float*)d_in[0];
    const float* feat  = (const float*)d_in[1];
    const int*   label = (const int*)d_in[2];
    const int*   step  = (const int*)d_in[3];
    float* out = (float*)d_out;
    const int n = in_sizes[2];

    char* ws = (char*)d_ws;
    int*   cursor     = (int*)(ws + OFF_CURSOR);
    int*   spill_cnt  = (int*)(ws + OFF_SPILLCNT);
    float* spill_sums = (float*)(ws + OFF_SPILLSUM);
    int*   spill_rows = (int*)(ws + OFF_SPILLROWS);
    int*   sorted     = (int*)(ws + OFF_SORTED);
    (void)ws_size;

    z0_zero   <<<(NCLASS + 1 + NCLASS * D + 1023) / 1024, 1024, 0, stream>>>((int*)ws);
    s1_scatter<<<1024, 512, 0, stream>>>(label, n / 4, cursor, sorted,
                                         spill_cnt, spill_rows);
    s2_spill  <<<64, 256, 0, stream>>>(feat, label, spill_cnt, spill_rows,
                                       spill_sums);
    k4_reduce <<<NCLASS, K4_TPB, 0, stream>>>(feat, sorted, cursor, spill_sums,
                                              proto, step, out);
}

// Round 7
// 197.328 us; speedup vs baseline: 2.5445x; 2.5445x over previous
//
#include <hip/hip_runtime.h>
#include <hip/hip_cooperative_groups.h>

namespace cg = cooperative_groups;

#define NCLASS 1000
#define D 64
#define WARMUP 1000
#define NB 256              // blocks in cooperative sort (1 per CU)
#define CT_TPB 1024
#define LAB_MAX 7936        // per-block label cache (n <= NB*LAB_MAX)
#define K4_TPB 1024
#define UNR 8               // k4: outstanding row-loads per thread

typedef float f32x4 __attribute__((ext_vector_type(4)));

// ws layout (bytes)
#define OFF_CNT   0          // NB*NCLASS ints (1.024 MB)  [b][c]
#define OFF_LOFF  1048576    // NB*NCLASS ints (1.024 MB)  [b][c]
#define OFF_TOT   2097152    // NCLASS ints
#define OFF_BASE  2101248    // NCLASS ints
#define OFF_SORT  2105344    // n ints (8 MB)

// ---------------------------------------------------------------------------
// Cooperative counting-sort: P1 histogram (labels cached in LDS) ->
// grid.sync -> P2 per-class cross-block scan -> grid.sync -> P3 base scan +
// LDS-cursor scatter (labels re-read from LDS, not HBM).
__global__ __launch_bounds__(CT_TPB)
void coop_sort(const int* __restrict__ label, int n, int rpb,
               int* __restrict__ cnt_t,      // [NB][NCLASS]
               int* __restrict__ loff_t,     // [NB][NCLASS]
               int* __restrict__ totals, int* __restrict__ base_g,
               int* __restrict__ sorted_idx)
{
    __shared__ int lab[LAB_MAX];
    __shared__ int hist[NCLASS];   // reused as scatter cursor in P3
    __shared__ int sbuf[CT_TPB];

    cg::grid_group grid = cg::this_grid();
    const int b = blockIdx.x, tid = threadIdx.x;
    const int r0 = b * rpb;
    const int cn = min(n - r0, rpb);

    // ---- P1: cache labels in LDS, LDS-atomic histogram ----
    for (int i = tid; i < cn; i += CT_TPB) lab[i] = label[r0 + i];
    if (tid < NCLASS) hist[tid] = 0;
    __syncthreads();
    for (int i = tid; i < cn; i += CT_TPB) atomicAdd(&hist[lab[i]], 1);
    __syncthreads();
    if (tid < NCLASS) cnt_t[b * NCLASS + tid] = hist[tid];

    grid.sync();

    // ---- P2: block b scans classes {b, b+256, b+512, b+768} over blocks ----
    {
        const int j  = tid >> 8;           // 0..3: which class of this block
        const int bp = tid & (NB - 1);     // block index being scanned
        const int c  = b + j * NB;
        const int v0 = (c < NCLASS) ? cnt_t[bp * NCLASS + c] : 0;
        sbuf[tid] = v0;
        __syncthreads();
        for (int off = 1; off < NB; off <<= 1) {
            const int add = (bp >= off) ? sbuf[tid - off] : 0;
            __syncthreads();
            sbuf[tid] += add;
            __syncthreads();
        }
        if (c < NCLASS) {
            loff_t[bp * NCLASS + c] = sbuf[tid] - v0;      // exclusive
            if (bp == NB - 1) totals[c] = sbuf[tid];       // inclusive tail
        }
    }

    grid.sync();

    // ---- P3: exclusive scan of totals -> base; cursor; scatter ----
    {
        const int mine = (tid < NCLASS) ? totals[tid] : 0;
        sbuf[tid] = mine;
        __syncthreads();
        for (int off = 1; off < CT_TPB; off <<= 1) {
            const int add = (tid >= off) ? sbuf[tid - off] : 0;
            __syncthreads();
            sbuf[tid] += add;
            __syncthreads();
        }
        if (tid < NCLASS) {
            const int bs = sbuf[tid] - mine;               // class base
            hist[tid] = bs + loff_t[b * NCLASS + tid];     // this block's cursor
            if (b == 0) base_g[tid] = bs;
        }
        __syncthreads();
        for (int i = tid; i < cn; i += CT_TPB) {
            const int pos = atomicAdd(&hist[lab[i]], 1);
            sorted_idx[pos] = r0 + i;
        }
    }
}

// ---------------------------------------------------------------------------
// K4: one block per class. Gather rows via sorted_idx, accumulate in
// registers (NO atomics), 8-deep unroll, non-temporal loads, shuffle+LDS
// reduce, fused mean/EMA finalize.
// Thread layout: slot = tid>>4 (64 row slots), col = tid&15 (float4 column).
__global__ __launch_bounds__(K4_TPB, 4)
void k4_reduce(const float* __restrict__ feat, const int* __restrict__ sorted_idx,
               const int* __restrict__ base, const int* __restrict__ totals,
               const float* __restrict__ proto, const int* __restrict__ step_ptr,
               float* __restrict__ out)
{
    __shared__ float red[16][D];
    const int c   = blockIdx.x;
    const int cnt = totals[c];
    const int st  = base[c];
    const int tid = threadIdx.x;
    const int slot = tid >> 4;
    const int col  = tid & 15;

    f32x4 acc0 = {0.f, 0.f, 0.f, 0.f};
    f32x4 acc1 = {0.f, 0.f, 0.f, 0.f};
    int j = slot;
    for (; j + (UNR - 1) * 64 < cnt; j += UNR * 64) {
        int rr[UNR];
        #pragma unroll
        for (int u = 0; u < UNR; ++u)
            rr[u] = sorted_idx[st + j + u * 64];
        f32x4 v[UNR];
        #pragma unroll
        for (int u = 0; u < UNR; ++u)
            v[u] = __builtin_nontemporal_load((const f32x4*)(feat + (size_t)rr[u] * D + col * 4));
        #pragma unroll
        for (int u = 0; u < UNR; u += 2) {
            acc0 += v[u];
            acc1 += v[u + 1];
        }
    }
    for (; j < cnt; j += 64) {
        const int r = sorted_idx[st + j];
        acc0 += __builtin_nontemporal_load((const f32x4*)(feat + (size_t)r * D + col * 4));
    }
    acc0 += acc1;

    // reduce the 4 slots within each wave (slot differs in tid bits 4-5)
    #pragma unroll
    for (int m = 16; m <= 32; m <<= 1) {
        acc0[0] += __shfl_xor(acc0[0], m);
        acc0[1] += __shfl_xor(acc0[1], m);
        acc0[2] += __shfl_xor(acc0[2], m);
        acc0[3] += __shfl_xor(acc0[3], m);
    }
    const int wv = tid >> 6;                 // wave id 0..15
    if ((tid & 63) < 16) {                   // lanes 0..15 hold col sums
        red[wv][col * 4 + 0] = acc0[0];
        red[wv][col * 4 + 1] = acc0[1];
        red[wv][col * 4 + 2] = acc0[2];
        red[wv][col * 4 + 3] = acc0[3];
    }
    __syncthreads();

    if (tid < D) {
        float s = 0.f;
        #pragma unroll
        for (int k = 0; k < 16; ++k) s += red[k][tid];
        const float mean = s / (float)(cnt > 0 ? cnt : 1);
        const float p    = proto[c * D + tid];
        const unsigned long long nz = __ballot(p != 0.0f);
        const bool use_new = (nz == 0ULL) || (step_ptr[0] <= WARMUP);
        const float upd = use_new ? mean : (0.9f * p + 0.1f * mean);
        out[c * D + tid] = (cnt > 0) ? upd : p;
    }
}

// ---------------------------------------------------------------------------
extern "C" void kernel_launch(void* const* d_in, const int* in_sizes, int n_in,
                              void* d_out, int out_size, void* d_ws, size_t ws_size,
                              hipStream_t stream)
{
    const float* proto = (const float*)d_in[0];
    const float* feat  = (const float*)d_in[1];
    const int*   label = (const int*)d_in[2];
    const int*   step  = (const int*)d_in[3];
    float* out = (float*)d_out;
    int n = in_sizes[2];

    char* ws = (char*)d_ws;
    int* cnt_t  = (int*)(ws + OFF_CNT);
    int* loff_t = (int*)(ws + OFF_LOFF);
    int* totals = (int*)(ws + OFF_TOT);
    int* base   = (int*)(ws + OFF_BASE);
    int* sorted = (int*)(ws + OFF_SORT);
    (void)ws_size;

    int rpb = (n + NB - 1) / NB;             // 7813 for n=2M; fits LAB_MAX

    void* args[] = { (void*)&label, (void*)&n, (void*)&rpb,
                     (void*)&cnt_t, (void*)&loff_t, (void*)&totals,
                     (void*)&base, (void*)&sorted };
    hipLaunchCooperativeKernel((void*)coop_sort, dim3(NB), dim3(CT_TPB),
                               args, 0, stream);

    k4_reduce<<<NCLASS, K4_TPB, 0, stream>>>(feat, sorted, base, totals,
                                             proto, step, out);
}

// Round 8
// 124.195 us; speedup vs baseline: 4.0428x; 1.5889x over previous
//
#include <hip/hip_runtime.h>

#define NCLASS 1000
#define D 64
#define WARMUP 1000
#define NB 256              // partition blocks (1 per CU)
#define LAB_MAX 7936        // per-block label cache (needs n <= NB*LAB_MAX)
#define K4_TPB 1024
#define UNR 8               // k4: outstanding row-loads per thread

typedef float f32x4 __attribute__((ext_vector_type(4)));

// ws layout (bytes)
#define OFF_CNT   0          // NCLASS*NB ints (1.024 MB)  [c][b]
#define OFF_LOFF  1048576    // NCLASS*NB ints (1.024 MB)  [c][b]
#define OFF_TOT   2097152    // NCLASS ints
#define OFF_BASE  2101248    // NCLASS ints
#define OFF_SORT  2105344    // n ints (8 MB)

// ---------------------------------------------------------------------------
// K1: per-block label histogram -> cnt_t[c * NB + b]  (transposed layout)
__global__ __launch_bounds__(512)
void k1_hist(const int* __restrict__ label, int n, int rpb,
             int* __restrict__ cnt_t)
{
    __shared__ int hist[NCLASS];
    const int b = blockIdx.x, tid = threadIdx.x;
    for (int i = tid; i < NCLASS; i += 512) hist[i] = 0;
    __syncthreads();
    const int r0 = b * rpb, r1 = min(n, r0 + rpb);
    for (int r = r0 + tid; r < r1; r += 512)
        atomicAdd(&hist[label[r]], 1);
    __syncthreads();
    for (int i = tid; i < NCLASS; i += 512)
        cnt_t[i * NB + b] = hist[i];
}

// ---------------------------------------------------------------------------
// K2: per-class exclusive scan across blocks -> loff_t[c][b]; last inclusive
// element is the class total.
__global__ __launch_bounds__(NB)
void k2_offsets(const int* __restrict__ cnt_t,
                int* __restrict__ loff_t, int* __restrict__ totals)
{
    __shared__ int buf[NB];
    const int c = blockIdx.x, t = threadIdx.x;
    const int v0 = cnt_t[c * NB + t];
    buf[t] = v0;
    __syncthreads();
    for (int off = 1; off < NB; off <<= 1) {
        const int v = (t >= off) ? buf[t - off] : 0;
        __syncthreads();
        buf[t] += v;
        __syncthreads();
    }
    loff_t[c * NB + t] = buf[t] - v0;
    if (t == NB - 1) totals[c] = buf[t];
}

// ---------------------------------------------------------------------------
// K3: write-coalesced scatter. Counting-sort the block's chunk in LDS
// (hist -> scan -> local scatter), then walk the LDS-sorted list in order:
// element k of class c goes to combo[c] + k, so consecutive lanes hit
// consecutive addresses within each class run (~8 ints = 32B bursts instead
// of 64 scattered 4B sectors per wave — kills the 11x write amplification
// measured on R6's s1_scatter).
__global__ __launch_bounds__(1024)
void k3_scatter(const int* __restrict__ label, int n, int rpb,
                const int* __restrict__ loff_t, const int* __restrict__ totals,
                int* __restrict__ sorted_idx, int* __restrict__ base_out)
{
    __shared__ int lab[LAB_MAX];     // chunk labels
    __shared__ int loc[LAB_MAX];     // locally sorted local row ids
    __shared__ int lstart[NCLASS];   // local class start (excl scan of hist)
    __shared__ int cursor[NCLASS];   // hist -> scatter cursor -> combo
    __shared__ int sbuf[1024];       // scan scratch

    const int b = blockIdx.x, tid = threadIdx.x;
    const int r0 = b * rpb;
    const int cn = min(n - r0, rpb);

    // P1: cache labels, local histogram (in `cursor`)
    for (int i = tid; i < cn; i += 1024) lab[i] = label[r0 + i];
    if (tid < NCLASS) cursor[tid] = 0;
    __syncthreads();
    for (int i = tid; i < cn; i += 1024) atomicAdd(&cursor[lab[i]], 1);
    __syncthreads();

    // P2: exclusive scan of local hist -> lstart; reset cursor to lstart
    {
        const int mine = (tid < NCLASS) ? cursor[tid] : 0;
        sbuf[tid] = mine;
        __syncthreads();
        for (int off = 1; off < 1024; off <<= 1) {
            const int add = (tid >= off) ? sbuf[tid - off] : 0;
            __syncthreads();
            sbuf[tid] += add;
            __syncthreads();
        }
        if (tid < NCLASS) {
            lstart[tid] = sbuf[tid] - mine;
            cursor[tid] = sbuf[tid] - mine;
        }
    }
    __syncthreads();

    // P3: local scatter into loc[] (LDS only)
    for (int i = tid; i < cn; i += 1024) {
        const int p = atomicAdd(&cursor[lab[i]], 1);
        loc[p] = i;
    }
    __syncthreads();

    // P4: global base scan (over totals) + combo = base + loff - lstart
    {
        const int mine = (tid < NCLASS) ? totals[tid] : 0;
        sbuf[tid] = mine;
        __syncthreads();
        for (int off = 1; off < 1024; off <<= 1) {
            const int add = (tid >= off) ? sbuf[tid - off] : 0;
            __syncthreads();
            sbuf[tid] += add;
            __syncthreads();
        }
        if (tid < NCLASS) {
            const int bs = sbuf[tid] - mine;
            if (b == 0) base_out[tid] = bs;
            cursor[tid] = bs + loff_t[tid * NB + b] - lstart[tid];
        }
    }
    __syncthreads();

    // P5: ordered write-out — consecutive k -> consecutive addr within runs
    for (int k = tid; k < cn; k += 1024) {
        const int lr = loc[k];
        const int c  = lab[lr];
        sorted_idx[cursor[c] + k] = r0 + lr;
    }
}

// ---------------------------------------------------------------------------
// K4: one block per class. Gather rows via sorted_idx, accumulate in
// registers (NO atomics), 8-deep unroll, non-temporal loads, shuffle+LDS
// reduce, fused mean/EMA finalize.
// Thread layout: slot = tid>>4 (64 row slots), col = tid&15 (float4 column).
__global__ __launch_bounds__(K4_TPB, 4)
void k4_reduce(const float* __restrict__ feat, const int* __restrict__ sorted_idx,
               const int* __restrict__ base, const int* __restrict__ totals,
               const float* __restrict__ proto, const int* __restrict__ step_ptr,
               float* __restrict__ out)
{
    __shared__ float red[16][D];
    const int c   = blockIdx.x;
    const int cnt = totals[c];
    const int st  = base[c];
    const int tid = threadIdx.x;
    const int slot = tid >> 4;
    const int col  = tid & 15;

    f32x4 acc0 = {0.f, 0.f, 0.f, 0.f};
    f32x4 acc1 = {0.f, 0.f, 0.f, 0.f};
    int j = slot;
    for (; j + (UNR - 1) * 64 < cnt; j += UNR * 64) {
        int rr[UNR];
        #pragma unroll
        for (int u = 0; u < UNR; ++u)
            rr[u] = sorted_idx[st + j + u * 64];
        f32x4 v[UNR];
        #pragma unroll
        for (int u = 0; u < UNR; ++u)
            v[u] = __builtin_nontemporal_load((const f32x4*)(feat + (size_t)rr[u] * D + col * 4));
        #pragma unroll
        for (int u = 0; u < UNR; u += 2) {
            acc0 += v[u];
            acc1 += v[u + 1];
        }
    }
    for (; j < cnt; j += 64) {
        const int r = sorted_idx[st + j];
        acc0 += __builtin_nontemporal_load((const f32x4*)(feat + (size_t)r * D + col * 4));
    }
    acc0 += acc1;

    // reduce the 4 slots within each wave (slot differs in tid bits 4-5)
    #pragma unroll
    for (int m = 16; m <= 32; m <<= 1) {
        acc0[0] += __shfl_xor(acc0[0], m);
        acc0[1] += __shfl_xor(acc0[1], m);
        acc0[2] += __shfl_xor(acc0[2], m);
        acc0[3] += __shfl_xor(acc0[3], m);
    }
    const int wv = tid >> 6;                 // wave id 0..15
    if ((tid & 63) < 16) {                   // lanes 0..15 hold col sums
        red[wv][col * 4 + 0] = acc0[0];
        red[wv][col * 4 + 1] = acc0[1];
        red[wv][col * 4 + 2] = acc0[2];
        red[wv][col * 4 + 3] = acc0[3];
    }
    __syncthreads();

    if (tid < D) {
        float s = 0.f;
        #pragma unroll
        for (int k = 0; k < 16; ++k) s += red[k][tid];
        const float mean = s / (float)(cnt > 0 ? cnt : 1);
        const float p    = proto[c * D + tid];
        const unsigned long long nz = __ballot(p != 0.0f);
        const bool use_new = (nz == 0ULL) || (step_ptr[0] <= WARMUP);
        const float upd = use_new ? mean : (0.9f * p + 0.1f * mean);
        out[c * D + tid] = (cnt > 0) ? upd : p;
    }
}

// ---------------------------------------------------------------------------
extern "C" void kernel_launch(void* const* d_in, const int* in_sizes, int n_in,
                              void* d_out, int out_size, void* d_ws, size_t ws_size,
                              hipStream_t stream)
{
    const float* proto = (const float*)d_in[0];
    const float* feat  = (const float*)d_in[1];
    const int*   label = (const int*)d_in[2];
    const int*   step  = (const int*)d_in[3];
    float* out = (float*)d_out;
    const int n = in_sizes[2];

    char* ws = (char*)d_ws;
    int* cnt_t  = (int*)(ws + OFF_CNT);
    int* loff_t = (int*)(ws + OFF_LOFF);
    int* totals = (int*)(ws + OFF_TOT);
    int* base   = (int*)(ws + OFF_BASE);
    int* sorted = (int*)(ws + OFF_SORT);
    (void)ws_size;

    const int rpb = (n + NB - 1) / NB;       // 7813 for n=2M; fits LAB_MAX

    k1_hist   <<<NB, 512, 0, stream>>>(label, n, rpb, cnt_t);
    k2_offsets<<<NCLASS, NB, 0, stream>>>(cnt_t, loff_t, totals);
    k3_scatter<<<NB, 1024, 0, stream>>>(label, n, rpb, loff_t, totals,
                                        sorted, base);
    k4_reduce <<<NCLASS, K4_TPB, 0, stream>>>(feat, sorted, base, totals,
                                              proto, step, out);
}

// Round 9
// 115.833 us; speedup vs baseline: 4.3346x; 1.0722x over previous
//
#include <hip/hip_runtime.h>

#define NCLASS 1000
#define D 64
#define WARMUP 1000
#define NB 256              // partition blocks (1 per CU)
#define LAB_MAX 7936        // per-block label cache (needs n <= NB*LAB_MAX)
#define K4_TPB 256          // 4 waves; 8 blocks/CU -> all 1000 classes resident
#define UNR 4               // k4: outstanding row-loads per thread

typedef float f32x4 __attribute__((ext_vector_type(4)));

// ws layout (bytes)
#define OFF_CNT   0          // NCLASS*NB ints (1.024 MB)  [c][b]
#define OFF_LOFF  1048576    // NCLASS*NB ints (1.024 MB)  [c][b]
#define OFF_TOT   2097152    // NCLASS ints
#define OFF_BASE  2101248    // NCLASS ints
#define OFF_SORT  2105344    // n ints (8 MB)

// ---------------------------------------------------------------------------
// K1: per-block label histogram -> cnt_t[c * NB + b]  (transposed layout)
__global__ __launch_bounds__(512)
void k1_hist(const int* __restrict__ label, int n, int rpb,
             int* __restrict__ cnt_t)
{
    __shared__ int hist[NCLASS];
    const int b = blockIdx.x, tid = threadIdx.x;
    for (int i = tid; i < NCLASS; i += 512) hist[i] = 0;
    __syncthreads();
    const int r0 = b * rpb, r1 = min(n, r0 + rpb);
    for (int r = r0 + tid; r < r1; r += 512)
        atomicAdd(&hist[label[r]], 1);
    __syncthreads();
    for (int i = tid; i < NCLASS; i += 512)
        cnt_t[i * NB + b] = hist[i];
}

// ---------------------------------------------------------------------------
// K2: per-class exclusive scan across blocks -> loff_t[c][b]; last inclusive
// element is the class total.
__global__ __launch_bounds__(NB)
void k2_offsets(const int* __restrict__ cnt_t,
                int* __restrict__ loff_t, int* __restrict__ totals)
{
    __shared__ int buf[NB];
    const int c = blockIdx.x, t = threadIdx.x;
    const int v0 = cnt_t[c * NB + t];
    buf[t] = v0;
    __syncthreads();
    for (int off = 1; off < NB; off <<= 1) {
        const int v = (t >= off) ? buf[t - off] : 0;
        __syncthreads();
        buf[t] += v;
        __syncthreads();
    }
    loff_t[c * NB + t] = buf[t] - v0;
    if (t == NB - 1) totals[c] = buf[t];
}

// ---------------------------------------------------------------------------
// K3: write-coalesced scatter (LDS counting-sort then ordered write-out).
__global__ __launch_bounds__(1024)
void k3_scatter(const int* __restrict__ label, int n, int rpb,
                const int* __restrict__ loff_t, const int* __restrict__ totals,
                int* __restrict__ sorted_idx, int* __restrict__ base_out)
{
    __shared__ int lab[LAB_MAX];     // chunk labels
    __shared__ int loc[LAB_MAX];     // locally sorted local row ids
    __shared__ int lstart[NCLASS];   // local class start (excl scan of hist)
    __shared__ int cursor[NCLASS];   // hist -> scatter cursor -> combo
    __shared__ int sbuf[1024];       // scan scratch

    const int b = blockIdx.x, tid = threadIdx.x;
    const int r0 = b * rpb;
    const int cn = min(n - r0, rpb);

    // P1: cache labels, local histogram (in `cursor`)
    for (int i = tid; i < cn; i += 1024) lab[i] = label[r0 + i];
    if (tid < NCLASS) cursor[tid] = 0;
    __syncthreads();
    for (int i = tid; i < cn; i += 1024) atomicAdd(&cursor[lab[i]], 1);
    __syncthreads();

    // P2: exclusive scan of local hist -> lstart; reset cursor to lstart
    {
        const int mine = (tid < NCLASS) ? cursor[tid] : 0;
        sbuf[tid] = mine;
        __syncthreads();
        for (int off = 1; off < 1024; off <<= 1) {
            const int add = (tid >= off) ? sbuf[tid - off] : 0;
            __syncthreads();
            sbuf[tid] += add;
            __syncthreads();
        }
        if (tid < NCLASS) {
            lstart[tid] = sbuf[tid] - mine;
            cursor[tid] = sbuf[tid] - mine;
        }
    }
    __syncthreads();

    // P3: local scatter into loc[] (LDS only)
    for (int i = tid; i < cn; i += 1024) {
        const int p = atomicAdd(&cursor[lab[i]], 1);
        loc[p] = i;
    }
    __syncthreads();

    // P4: global base scan (over totals) + combo = base + loff - lstart
    {
        const int mine = (tid < NCLASS) ? totals[tid] : 0;
        sbuf[tid] = mine;
        __syncthreads();
        for (int off = 1; off < 1024; off <<= 1) {
            const int add = (tid >= off) ? sbuf[tid - off] : 0;
            __syncthreads();
            sbuf[tid] += add;
            __syncthreads();
        }
        if (tid < NCLASS) {
            const int bs = sbuf[tid] - mine;
            if (b == 0) base_out[tid] = bs;
            cursor[tid] = bs + loff_t[tid * NB + b] - lstart[tid];
        }
    }
    __syncthreads();

    // P5: ordered write-out — consecutive k -> consecutive addr within runs
    for (int k = tid; k < cn; k += 1024) {
        const int lr = loc[k];
        const int c  = lab[lr];
        sorted_idx[cursor[c] + k] = r0 + lr;
    }
}

// ---------------------------------------------------------------------------
// K4: one 256-thread block per class, ALL 1000 blocks co-resident (8/CU) so
// every class sweeps the feature array in lockstep — the aggregate DRAM
// access pattern becomes a tight moving window instead of desynchronized
// cohorts. Register accumulate, shuffle+LDS reduce, fused mean/EMA finalize.
// Thread layout: slot = tid>>4 (16 row slots), col = tid&15 (float4 column).
__global__ __launch_bounds__(K4_TPB, 8)
void k4_reduce(const float* __restrict__ feat, const int* __restrict__ sorted_idx,
               const int* __restrict__ base, const int* __restrict__ totals,
               const float* __restrict__ proto, const int* __restrict__ step_ptr,
               float* __restrict__ out)
{
    __shared__ float red[4][D];
    const int c   = blockIdx.x;
    const int cnt = totals[c];
    const int st  = base[c];
    const int tid = threadIdx.x;
    const int slot = tid >> 4;               // 0..15
    const int col  = tid & 15;

    f32x4 acc0 = {0.f, 0.f, 0.f, 0.f};
    f32x4 acc1 = {0.f, 0.f, 0.f, 0.f};
    int j = slot;
    for (; j + (UNR - 1) * 16 < cnt; j += UNR * 16) {
        int rr[UNR];
        #pragma unroll
        for (int u = 0; u < UNR; ++u)
            rr[u] = sorted_idx[st + j + u * 16];
        f32x4 v[UNR];
        #pragma unroll
        for (int u = 0; u < UNR; ++u)
            v[u] = __builtin_nontemporal_load((const f32x4*)(feat + (size_t)rr[u] * D + col * 4));
        #pragma unroll
        for (int u = 0; u < UNR; u += 2) {
            acc0 += v[u];
            acc1 += v[u + 1];
        }
    }
    for (; j < cnt; j += 16) {
        const int r = sorted_idx[st + j];
        acc0 += __builtin_nontemporal_load((const f32x4*)(feat + (size_t)r * D + col * 4));
    }
    acc0 += acc1;

    // reduce the 4 slots within each wave (slot differs in tid bits 4-5)
    #pragma unroll
    for (int m = 16; m <= 32; m <<= 1) {
        acc0[0] += __shfl_xor(acc0[0], m);
        acc0[1] += __shfl_xor(acc0[1], m);
        acc0[2] += __shfl_xor(acc0[2], m);
        acc0[3] += __shfl_xor(acc0[3], m);
    }
    const int wv = tid >> 6;                 // wave id 0..3
    if ((tid & 63) < 16) {                   // lanes 0..15 hold col sums
        red[wv][col * 4 + 0] = acc0[0];
        red[wv][col * 4 + 1] = acc0[1];
        red[wv][col * 4 + 2] = acc0[2];
        red[wv][col * 4 + 3] = acc0[3];
    }
    __syncthreads();

    if (tid < D) {
        float s = 0.f;
        #pragma unroll
        for (int k = 0; k < 4; ++k) s += red[k][tid];
        const float mean = s / (float)(cnt > 0 ? cnt : 1);
        const float p    = proto[c * D + tid];
        const unsigned long long nz = __ballot(p != 0.0f);
        const bool use_new = (nz == 0ULL) || (step_ptr[0] <= WARMUP);
        const float upd = use_new ? mean : (0.9f * p + 0.1f * mean);
        out[c * D + tid] = (cnt > 0) ? upd : p;
    }
}

// ---------------------------------------------------------------------------
extern "C" void kernel_launch(void* const* d_in, const int* in_sizes, int n_in,
                              void* d_out, int out_size, void* d_ws, size_t ws_size,
                              hipStream_t stream)
{
    const float* proto = (const float*)d_in[0];
    const float* feat  = (const float*)d_in[1];
    const int*   label = (const int*)d_in[2];
    const int*   step  = (const int*)d_in[3];
    float* out = (float*)d_out;
    const int n = in_sizes[2];

    char* ws = (char*)d_ws;
    int* cnt_t  = (int*)(ws + OFF_CNT);
    int* loff_t = (int*)(ws + OFF_LOFF);
    int* totals = (int*)(ws + OFF_TOT);
    int* base   = (int*)(ws + OFF_BASE);
    int* sorted = (int*)(ws + OFF_SORT);
    (void)ws_size;

    const int rpb = (n + NB - 1) / NB;       // 7813 for n=2M; fits LAB_MAX

    k1_hist   <<<NB, 512, 0, stream>>>(label, n, rpb, cnt_t);
    k2_offsets<<<NCLASS, NB, 0, stream>>>(cnt_t, loff_t, totals);
    k3_scatter<<<NB, 1024, 0, stream>>>(label, n, rpb, loff_t, totals,
                                        sorted, base);
    k4_reduce <<<NCLASS, K4_TPB, 0, stream>>>(feat, sorted, base, totals,
                                              proto, step, out);
}